// Round 9
// baseline (1489.040 us; speedup 1.0000x reference)
//
#include <hip/hip_runtime.h>
#include <stdint.h>

namespace {
constexpr int kB = 64, kT = 4096, kDin = 64, kDe = 24, kH = 128;
constexpr int kCh = 16;                 // steps per pre-chunk
constexpr int kNCh = kT / kCh;          // 256 chunks
constexpr int kRowU = 16;               // uints per padded e row (24 f16 + 8 zero)
constexpr int kPS = 20;                 // preh stride per (g,u) in floats (pad 16->20)
constexpr float kLog2e = 1.4426950408889634f;

typedef __attribute__((ext_vector_type(8))) _Float16 frag8;   // f16 MFMA A/B
typedef __attribute__((ext_vector_type(4))) float v4f;        // MFMA C/D
typedef __attribute__((ext_vector_type(8))) int v8i;          // f8f6f4 MFMA A/B
typedef __attribute__((ext_vector_type(4))) int v4i;
union H2U { uint32_t u; _Float16 s[2]; };

__device__ __forceinline__ float rcp_fast(float x){
#if __has_builtin(__builtin_amdgcn_rcpf)
  return __builtin_amdgcn_rcpf(x);
#else
  return 1.0f / x;
#endif
}
__device__ __forceinline__ float exp2_f(float x){
#if __has_builtin(__builtin_amdgcn_exp2f)
  return __builtin_amdgcn_exp2f(x);
#else
  return exp2f(x);
#endif
}
__device__ __forceinline__ float sigmoid_f(float x){
  return rcp_fast(1.0f + __expf(-x));
}
__device__ __forceinline__ uint32_t pack2(float lo, float hi){
  H2U u; u.s[0] = (_Float16)lo; u.s[1] = (_Float16)hi; return u.u;
}
// e2m1 fp4 encode, round-to-nearest: codes {0,.5,1,1.5,2,3,4,6}, clamp to 6.
__device__ __forceinline__ uint32_t fp4enc(float x){
  uint32_t s = (x < 0.0f) ? 8u : 0u;
  float a = fabsf(x);
  uint32_t c = (a < 0.25f) ? 0u :
               (a < 0.75f) ? 1u :
               (a < 1.25f) ? 2u :
               (a < 1.75f) ? 3u :
               (a < 2.5f)  ? 4u :
               (a < 3.5f)  ? 5u :
               (a < 5.0f)  ? 6u : 7u;
  return s | c;
}
// pack two floats -> one fp4 byte (lo nibble = a, hi nibble = b)
__device__ __forceinline__ uint32_t fp4pk(float a, float b){
#if __has_builtin(__builtin_amdgcn_cvt_scalef32_pk_fp4_f32)
  return __builtin_amdgcn_cvt_scalef32_pk_fp4_f32(0u, a, b, 1.0f, 0) & 0xffu;
#else
  return fp4enc(a) | (fp4enc(b) << 4);
#endif
}
__device__ __forceinline__ float dpp_xor1(float x){
#if __has_builtin(__builtin_amdgcn_mov_dpp)
  // quad_perm [1,0,3,2] = 0xB1: swap adjacent lanes, VALU-speed (no DS pipe)
  return __int_as_float(__builtin_amdgcn_mov_dpp(__float_as_int(x), 0xB1, 0xF, 0xF, true));
#else
  return __shfl_xor(x, 1, 64);
#endif
}
// Barrier that only drains LDS ops (h-write visibility); the e-prefetch
// global_load stays in flight across barriers (no vmcnt(0) per step).
__device__ __forceinline__ void lgkm_barrier(){
  asm volatile("s_waitcnt lgkmcnt(0)" ::: "memory");
  __builtin_amdgcn_sched_barrier(0);
  __builtin_amdgcn_s_barrier();
  __builtin_amdgcn_sched_barrier(0);
  asm volatile("" ::: "memory");
}
} // namespace

// Kernel 1 (parallel): e[b,t,:] = sigmoid(x[b,t,:] @ W_emb + b_emb), packed f16,
// rows padded to 32 f16 (last 8 = 0).
__global__ __launch_bounds__(256) void emb_kernel(
    const float* __restrict__ x, const float* __restrict__ W,
    const float* __restrict__ bias, uint32_t* __restrict__ e_out)
{
  int r = blockIdx.x * blockDim.x + threadIdx.x;
  if (r >= kB * kT) return;
  const float4* xr = (const float4*)(x + (size_t)r * kDin);
  float acc[kDe];
#pragma unroll
  for (int k = 0; k < kDe; ++k) acc[k] = bias[k];
#pragma unroll 4
  for (int d4 = 0; d4 < kDin / 4; ++d4){
    float4 xv = xr[d4];
    const float* w0 = W + (size_t)(d4 * 4) * kDe;
#pragma unroll
    for (int k = 0; k < kDe; ++k) acc[k] += xv.x * w0[k];
#pragma unroll
    for (int k = 0; k < kDe; ++k) acc[k] += xv.y * w0[kDe + k];
#pragma unroll
    for (int k = 0; k < kDe; ++k) acc[k] += xv.z * w0[2 * kDe + k];
#pragma unroll
    for (int k = 0; k < kDe; ++k) acc[k] += xv.w * w0[3 * kDe + k];
  }
  uint32_t p[12];
#pragma unroll
  for (int k = 0; k < 12; ++k)
    p[k] = pack2(sigmoid_f(acc[2 * k]), sigmoid_f(acc[2 * k + 1]));
  uint4* dst = (uint4*)(e_out + (size_t)r * kRowU);
  dst[0] = make_uint4(p[0], p[1], p[2],  p[3]);
  dst[1] = make_uint4(p[4], p[5], p[6],  p[7]);
  dst[2] = make_uint4(p[8], p[9], p[10], p[11]);
  dst[3] = make_uint4(0u, 0u, 0u, 0u);
}

// Kernel 2: one block (512 thr, 8 waves) per batch chain.
// Round-9 = round-6 fp4 kernel with the occupancy/VGPR knob applied the
// DOCUMENTED way: __launch_bounds__(512, 2) — 2nd arg is min waves per EU,
// raising the VGPR cap to 512-per-SIMD/2 = 256/wave while our 8-wave block
// needs exactly 2 waves/SIMD. Rounds 5/6/8 were pinned at cap 128 (bare
// amdgpu_waves_per_eu attribute was ignored; VGPR_Count stayed 128) and the
// fp4 live set (~145 regs) spilled every step (WRITE_SIZE 15.9MB scratch
// leak on the serial chain). fp4 numerics unchanged (HW-verified, absmax 0).
__global__ __launch_bounds__(512, 2)
void lstm_kernel(
    const uint32_t* __restrict__ e_ws,
    const float* __restrict__ W_f, const float* __restrict__ b_f,
    const float* __restrict__ W_i, const float* __restrict__ b_i,
    const float* __restrict__ W_c, const float* __restrict__ b_c,
    const float* __restrict__ W_o, const float* __restrict__ b_o,
    const float* __restrict__ W_out, const float* __restrict__ b_out,
    float* __restrict__ out)
{
  __shared__ __align__(16) float preh[4 * kH * kPS];      // 40 KB [g][u][s pad 20]
  __shared__ __align__(16) uint32_t elds[kCh * kRowU];    // 1 KB e chunk (f16)
  __shared__ __align__(64) uint32_t hfp4[2 * 16];         // 2 x 64 B h (fp4 x4)
  __shared__ float red[8];

  const int b  = blockIdx.x;
  const int t0 = threadIdx.x;
  const int w  = t0 >> 6;
  const int l  = t0 & 63;
  const int q  = l >> 4;
  const int cl = l & 15;
  const int u  = w * 16 + cl;      // hidden unit owned

  const float* Wg[4] = {W_f, W_i, W_c, W_o};
  const float* bgp[4] = {b_f, b_i, b_c, b_o};
  // negative prescale: sigmoid(x) = rcp(1+exp2(-log2e*x)); tanh(x) =
  // 2*rcp(1+exp2(-2log2e*x)) - 1.  Gate order: 0=f 1=i 2=g(tanh) 3=o.
  const float scl[4] = {-kLog2e, -kLog2e, -2.0f * kLog2e, -kLog2e};

  // fp4 B-frags for the h-GEMM: B[k][n]: n = u, k = q*32 + r*8 + nibble,
  // W row = 24 + k. f/i/o stored w*scl*64 (scale 2^-6), c stored w*scl*32
  // (scale 2^-5) to keep the 2x-prescaled tanh weights off the e2m1 clamp.
  v8i B4[4];
#pragma unroll
  for (int g = 0; g < 4; ++g){
    const float sc = scl[g] * ((g == 2) ? 32.0f : 64.0f);
#pragma unroll
    for (int r = 0; r < 4; ++r){
      const float* col = Wg[g] + (size_t)(24 + q * 32 + r * 8) * kH + u;
      uint32_t d = 0;
#pragma unroll
      for (int n = 0; n < 8; ++n)
        d |= fp4enc(col[(size_t)n * kH] * sc) << (4 * n);
      B4[g][r] = (int)d;
    }
    B4[g][4] = 0; B4[g][5] = 0; B4[g][6] = 0; B4[g][7] = 0;
  }

  // f16 B-frags for the pre-GEMM (e-part, K=32 padded from 24), prescaled
  frag8 Bp[4];
  float biasC[4];
#pragma unroll
  for (int g = 0; g < 4; ++g){
    biasC[g] = bgp[g][u] * scl[g];
#pragma unroll
    for (int j = 0; j < 8; ++j){
      int k = q * 8 + j;
      Bp[g][j] = (_Float16)((k < kDe) ? Wg[g][(size_t)k * kH + u] * scl[g] : 0.0f);
    }
  }

  const uint4* e4 = (const uint4*)e_ws;          // 4 uint4 per (b,t) row
  const size_t bbase = (size_t)b * kT * 4;

  // pre-GEMM: A rows = 16 steps from elds; D[step][unit] -> preh[g][u][step]
  auto do_pregemm = [&](){
    frag8 Ae = *(const frag8*)&elds[cl * kRowU + q * 4];  // A[m=cl][k=q*8+j]
#pragma unroll
    for (int g = 0; g < 4; ++g){
      v4f c; c[0] = biasC[g]; c[1] = biasC[g]; c[2] = biasC[g]; c[3] = biasC[g];
      v4f d = __builtin_amdgcn_mfma_f32_16x16x32_f16(Ae, Bp[g], c, 0, 0, 0);
      // lane (q,cl) holds steps q*4+r for unit u -> one aligned b128 write
      *(v4f*)&preh[(g * kH + u) * kPS + q * 4] = d;
    }
  };
  // chunk-wide pre prefetch: packed f16 pairs -> 8 u32 regs per gate
  uint32_t pbp[4][kCh / 2];
  auto load_pb = [&](){
#pragma unroll
    for (int g = 0; g < 4; ++g){
      const v4f* src = (const v4f*)&preh[(g * kH + u) * kPS];
#pragma unroll
      for (int r = 0; r < 4; ++r){
        v4f t = src[r];
        pbp[g][2 * r]     = pack2(t[0], t[1]);
        pbp[g][2 * r + 1] = pack2(t[2], t[3]);
      }
    }
  };
  // unpack gate g's pre-act for step s (s compile-time in the unrolled loop)
  auto upb = [&](int g, int s) -> float {
    H2U t; t.u = pbp[g][s >> 1]; return (float)t.s[s & 1];
  };

  // startup: e chunk 0 -> elds; h = 0; pre-GEMM chunk 0; prefetch chunk 1
  uint4 pre4;
  if (t0 < 64) ((uint4*)elds)[t0] = e4[bbase + t0];
  if (t0 < 32) hfp4[t0] = 0u;      // fp4 code 0 == 0.0
  __syncthreads();
  do_pregemm();
  load_pb();
  if (t0 < 64 && kNCh > 1) pre4 = e4[bbase + (size_t)kCh * 4 + t0];

  float cst = 0.0f, ho = 0.0f;     // ho = 4*tanh(c)*o (fp4-scaled h)
  const v4f zero4 = {0.0f, 0.0f, 0.0f, 0.0f};
  const v4i zer4i = {0, 0, 0, 0};
  const bool writer = (l < 16) && ((cl & 1) == 0);

#pragma unroll 1
  for (int cc = 0; cc < kNCh; ++cc){
#pragma unroll
    for (int s = 0; s < kCh; ++s){
      const int cur = (cc * kCh + s) & 1, nxt = cur ^ 1;

      // A: 16 fp4-packed h-bytes (k = 2*byte + nibble); SSA widen, no
      // address-taken.
      v4i Alo = *(const v4i*)((const uint8_t*)hfp4 + cur * 64 + q * 16);
      v8i A8 = __builtin_shufflevector(Alo, zer4i, 0, 1, 2, 3, 4, 5, 6, 7);

      v4f a0 = __builtin_amdgcn_mfma_scale_f32_16x16x128_f8f6f4(
                   A8, B4[0], zero4, 4, 4, 0, 125, 0, 121);
      v4f a1 = __builtin_amdgcn_mfma_scale_f32_16x16x128_f8f6f4(
                   A8, B4[1], zero4, 4, 4, 0, 125, 0, 121);
      v4f a2 = __builtin_amdgcn_mfma_scale_f32_16x16x128_f8f6f4(
                   A8, B4[2], zero4, 4, 4, 0, 125, 0, 122);
      v4f a3 = __builtin_amdgcn_mfma_scale_f32_16x16x128_f8f6f4(
                   A8, B4[3], zero4, 4, 4, 0, 125, 0, 121);

      // all four prescaled gate pre-acts are lane-local (D rows identical)
      float f  = rcp_fast(1.0f + exp2_f(a0[0] + upb(0, s)));
      float ig = rcp_fast(1.0f + exp2_f(a1[0] + upb(1, s)));
      float g2 = rcp_fast(1.0f + exp2_f(a2[0] + upb(2, s)));
      float og = rcp_fast(1.0f + exp2_f(a3[0] + upb(3, s)));
      float gg = fmaf(g2, 2.0f, -1.0f);                   // tanh gate
      cst = fmaf(cst, f, ig * gg);
      float rh = rcp_fast(1.0f + exp2_f(-2.0f * kLog2e * cst));
      ho = fmaf(rh, 8.0f, -4.0f) * og;                    // 4*tanh(c)*o

      // pair units (u even, u+1) into one fp4 byte; DPP swap is VALU-speed
      float ho2 = dpp_xor1(ho);
      if (writer){
        uint32_t byte = fp4pk(ho, ho2);
        ((uint8_t*)hfp4)[nxt * 64 + w * 8 + (cl >> 1)] = (uint8_t)byte;
      }
      // last step of chunk: commit prefetched e before the barrier
      if (s == kCh - 1 && cc + 1 < kNCh && t0 < 64) ((uint4*)elds)[t0] = pre4;
      lgkm_barrier();
    }

    if (cc + 1 < kNCh){
      do_pregemm();                // reads elds (barriered), writes preh
      load_pb();                   // intra-wave, lgkmcnt only
      if (t0 < 64 && cc + 2 < kNCh)
        pre4 = e4[bbase + (size_t)(cc + 2) * kCh * 4 + t0];
    }
  }

  // epilogue: out[b] = sigmoid(h_T @ W_out + b_out); h_T = ho/4
  float partial = (l < 16) ? ho * (W_out[u] * 0.25f) : 0.0f;
#pragma unroll
  for (int off = 1; off <= 32; off <<= 1) partial += __shfl_xor(partial, off, 64);
  if (l == 0) red[w] = partial;
  __syncthreads();
  if (t0 == 0){
    float acc = b_out[0];
#pragma unroll
    for (int k = 0; k < 8; ++k) acc += red[k];
    out[b] = sigmoid_f(acc);
  }
}

extern "C" void kernel_launch(void* const* d_in, const int* in_sizes, int n_in,
                              void* d_out, int out_size, void* d_ws, size_t ws_size,
                              hipStream_t stream){
  const float* x     = (const float*)d_in[0];
  const float* W_emb = (const float*)d_in[1];
  const float* b_emb = (const float*)d_in[2];
  const float* W_f   = (const float*)d_in[3];
  const float* b_f   = (const float*)d_in[4];
  const float* W_i   = (const float*)d_in[5];
  const float* b_i   = (const float*)d_in[6];
  const float* W_c   = (const float*)d_in[7];
  const float* b_c   = (const float*)d_in[8];
  const float* W_o   = (const float*)d_in[9];
  const float* b_o   = (const float*)d_in[10];
  const float* W_out = (const float*)d_in[11];
  const float* b_out = (const float*)d_in[12];
  float* out = (float*)d_out;
  uint32_t* e_ws = (uint32_t*)d_ws;    // B*T*16*4 = 16.8 MB

  const int rows = kB * kT;
  emb_kernel<<<(rows + 255) / 256, 256, 0, stream>>>(x, W_emb, b_emb, e_ws);
  lstm_kernel<<<kB, 512, 0, stream>>>(e_ws, W_f, b_f, W_i, b_i, W_c, b_c,
                                      W_o, b_o, W_out, b_out, out);
}

// Round 10
// 1447.966 us; speedup vs baseline: 1.0284x; 1.0284x over previous
//
#include <hip/hip_runtime.h>
#include <stdint.h>

namespace {
constexpr int kB = 64, kT = 4096, kDin = 64, kDe = 24, kH = 128;
constexpr int kCh = 16;                 // steps per pre-chunk
constexpr int kNCh = kT / kCh;          // 256 chunks
constexpr int kRowU = 16;               // uints per padded e row (24 f16 + 8 zero)
constexpr int kPS = 20;                 // preh stride per (g,u) in floats (pad 16->20)
constexpr float kLog2e = 1.4426950408889634f;

typedef __attribute__((ext_vector_type(8))) _Float16 frag8;   // f16 MFMA A/B
typedef __attribute__((ext_vector_type(4))) float v4f;        // MFMA C/D
typedef __attribute__((ext_vector_type(8))) int v8i;          // fp8 MFMA A/B
union H2U { uint32_t u; _Float16 s[2]; };

__device__ __forceinline__ float rcp_fast(float x){
#if __has_builtin(__builtin_amdgcn_rcpf)
  return __builtin_amdgcn_rcpf(x);
#else
  return 1.0f / x;
#endif
}
__device__ __forceinline__ float exp2_f(float x){
#if __has_builtin(__builtin_amdgcn_exp2f)
  return __builtin_amdgcn_exp2f(x);
#else
  return exp2f(x);
#endif
}
__device__ __forceinline__ float sigmoid_f(float x){
  return rcp_fast(1.0f + __expf(-x));
}
__device__ __forceinline__ uint32_t pack2(float lo, float hi){
  H2U u; u.s[0] = (_Float16)lo; u.s[1] = (_Float16)hi; return u.u;
}
__device__ __forceinline__ uint32_t sw_fp8(float x){   // fallback e4m3 encode
  union{float f; uint32_t u;} v; v.f = x;
  uint32_t s = (v.u >> 24) & 0x80u;
  float a = fabsf(x);
  if (a < 0.0009765625f) return s;
  if (a > 448.0f) a = 448.0f;
  int e; float m = frexpf(a, &e);
  int E = e - 1 + 7;
  uint32_t bits;
  if (E <= 0){
    int q = (int)(a * 512.0f + 0.5f); if (q > 7) q = 7; bits = (uint32_t)q;
  } else {
    int q = (int)(m * 16.0f + 0.5f);
    if (q == 16){ q = 8; ++E; }
    if (E > 15) { E = 15; q = 14; }
    bits = ((uint32_t)E << 3) | ((uint32_t)q & 7u);
  }
  return s | bits;
}
template <bool HI>
__device__ __forceinline__ uint32_t fp8pair(float a, float b, uint32_t old){
#if __has_builtin(__builtin_amdgcn_cvt_pk_fp8_f32)
  return (uint32_t)__builtin_amdgcn_cvt_pk_fp8_f32(a, b, (int)old, HI);
#else
  uint32_t p = sw_fp8(a) | (sw_fp8(b) << 8);
  return HI ? ((old & 0x0000ffffu) | (p << 16)) : ((old & 0xffff0000u) | p);
#endif
}
// Barrier that only drains LDS ops (h-write visibility); the e-prefetch
// global_load stays in flight across barriers (no vmcnt(0) per step).
__device__ __forceinline__ void lgkm_barrier(){
  asm volatile("s_waitcnt lgkmcnt(0)" ::: "memory");
  __builtin_amdgcn_sched_barrier(0);
  __builtin_amdgcn_s_barrier();
  __builtin_amdgcn_sched_barrier(0);
  asm volatile("" ::: "memory");
}
} // namespace

// Kernel 1 (parallel): e[b,t,:] = sigmoid(x[b,t,:] @ W_emb + b_emb), packed f16,
// rows padded to 32 f16 (last 8 = 0).
__global__ __launch_bounds__(256) void emb_kernel(
    const float* __restrict__ x, const float* __restrict__ W,
    const float* __restrict__ bias, uint32_t* __restrict__ e_out)
{
  int r = blockIdx.x * blockDim.x + threadIdx.x;
  if (r >= kB * kT) return;
  const float4* xr = (const float4*)(x + (size_t)r * kDin);
  float acc[kDe];
#pragma unroll
  for (int k = 0; k < kDe; ++k) acc[k] = bias[k];
#pragma unroll 4
  for (int d4 = 0; d4 < kDin / 4; ++d4){
    float4 xv = xr[d4];
    const float* w0 = W + (size_t)(d4 * 4) * kDe;
#pragma unroll
    for (int k = 0; k < kDe; ++k) acc[k] += xv.x * w0[k];
#pragma unroll
    for (int k = 0; k < kDe; ++k) acc[k] += xv.y * w0[kDe + k];
#pragma unroll
    for (int k = 0; k < kDe; ++k) acc[k] += xv.z * w0[2 * kDe + k];
#pragma unroll
    for (int k = 0; k < kDe; ++k) acc[k] += xv.w * w0[3 * kDe + k];
  }
  uint32_t p[12];
#pragma unroll
  for (int k = 0; k < 12; ++k)
    p[k] = pack2(sigmoid_f(acc[2 * k]), sigmoid_f(acc[2 * k + 1]));
  uint4* dst = (uint4*)(e_out + (size_t)r * kRowU);
  dst[0] = make_uint4(p[0], p[1], p[2],  p[3]);
  dst[1] = make_uint4(p[4], p[5], p[6],  p[7]);
  dst[2] = make_uint4(p[8], p[9], p[10], p[11]);
  dst[3] = make_uint4(0u, 0u, 0u, 0u);
}

// Kernel 2: one block (512 thr, 8 waves) per batch chain.
// Round-10 = revert to the round-3 fp8 kernel (best verified: 1342us lstm,
// WRITE 2KB, no scratch; fp4 abandoned — 5 configs, all flat: the FMT field
// on 16x16x128_f8f6f4 doesn't change pipe cycles) + two critical-path trims:
//  (1) MFMA issue order g,f,i,o: the tanh-gate (longest VALU consumer chain)
//      gets its result first; the o-gate (consumed only at the final mul)
//      arrives last — its exp2 overlaps the c-chain.
//  (2) c-state carried prescaled: cs2 = -2*log2e*cst, updated as
//      cs2 = fma(cs2, f, -2log2e*(ig*gg)) -> exp2(cs2) directly.
//      Removes one dependent mul from the longest per-step VALU chain.
__global__ __launch_bounds__(512, 1) void lstm_kernel(
    const uint32_t* __restrict__ e_ws,
    const float* __restrict__ W_f, const float* __restrict__ b_f,
    const float* __restrict__ W_i, const float* __restrict__ b_i,
    const float* __restrict__ W_c, const float* __restrict__ b_c,
    const float* __restrict__ W_o, const float* __restrict__ b_o,
    const float* __restrict__ W_out, const float* __restrict__ b_out,
    float* __restrict__ out)
{
  __shared__ __align__(16) float preh[4 * kH * kPS];      // 40 KB [g][u][s pad 20]
  __shared__ __align__(16) uint32_t elds[kCh * kRowU];    // 1 KB e chunk (f16)
  __shared__ __align__(64) uint32_t hfp8[2 * 32];         // 2 x 128 B h (fp8 x64)
  __shared__ float red[8];

  const int b  = blockIdx.x;
  const int t0 = threadIdx.x;
  const int w  = t0 >> 6;
  const int l  = t0 & 63;
  const int q  = l >> 4;
  const int cl = l & 15;
  const int u  = w * 16 + cl;      // hidden unit owned

  const float* Wg[4] = {W_f, W_i, W_c, W_o};
  const float* bgp[4] = {b_f, b_i, b_c, b_o};
  // negative prescale: sigmoid(x) = rcp(1+exp2(-log2e*x)); tanh(x) =
  // 2*rcp(1+exp2(-2log2e*x)) - 1.  Gate order: 0=f 1=i 2=g(tanh) 3=o.
  const float scl[4] = {-kLog2e, -kLog2e, -2.0f * kLog2e, -kLog2e};
  const float kM2L = -2.0f * kLog2e;

  // fp8 B-frags for the h-GEMM: B[k][n]: n = u, k = q*32 + r*4 + byte,
  // W row = 24 + k, stored value = w*64*scl[g] with E8M0 scale 2^-6 (121).
  v8i B8[4];
#pragma unroll
  for (int g = 0; g < 4; ++g){
    const float sc = scl[g] * 64.0f;
#pragma unroll
    for (int r = 0; r < 8; ++r){
      const float* col = Wg[g] + (size_t)(24 + q * 32 + r * 4) * kH + u;
      uint32_t reg = fp8pair<false>(col[0] * sc, col[kH] * sc, 0u);
      reg = fp8pair<true>(col[2 * kH] * sc, col[3 * kH] * sc, reg);
      B8[g][r] = (int)reg;
    }
  }

  // f16 B-frags for the pre-GEMM (e-part, K=32 padded from 24), prescaled
  frag8 Bp[4];
  float biasC[4];
#pragma unroll
  for (int g = 0; g < 4; ++g){
    biasC[g] = bgp[g][u] * scl[g];
#pragma unroll
    for (int j = 0; j < 8; ++j){
      int k = q * 8 + j;
      Bp[g][j] = (_Float16)((k < kDe) ? Wg[g][(size_t)k * kH + u] * scl[g] : 0.0f);
    }
  }

  const uint4* e4 = (const uint4*)e_ws;          // 4 uint4 per (b,t) row
  const size_t bbase = (size_t)b * kT * 4;

  // pre-GEMM: A rows = 16 steps from elds; D[step][unit] -> preh[g][u][step]
  auto do_pregemm = [&](){
    frag8 Ae = *(const frag8*)&elds[cl * kRowU + q * 4];  // A[m=cl][k=q*8+j]
#pragma unroll
    for (int g = 0; g < 4; ++g){
      v4f c; c[0] = biasC[g]; c[1] = biasC[g]; c[2] = biasC[g]; c[3] = biasC[g];
      v4f d = __builtin_amdgcn_mfma_f32_16x16x32_f16(Ae, Bp[g], c, 0, 0, 0);
      // lane (q,cl) holds steps q*4+r for unit u -> one aligned b128 write
      *(v4f*)&preh[(g * kH + u) * kPS + q * 4] = d;
    }
  };
  // chunk-wide pre prefetch: preh[g][u][0..15] -> 16 f32 regs per gate
  float pb[4][kCh];
  auto load_pb = [&](){
#pragma unroll
    for (int g = 0; g < 4; ++g){
      const v4f* src = (const v4f*)&preh[(g * kH + u) * kPS];
#pragma unroll
      for (int r = 0; r < 4; ++r){
        v4f t = src[r];
        pb[g][4*r+0] = t[0]; pb[g][4*r+1] = t[1];
        pb[g][4*r+2] = t[2]; pb[g][4*r+3] = t[3];
      }
    }
  };

  // startup: e chunk 0 -> elds; h = 0; pre-GEMM chunk 0; prefetch chunk 1
  uint4 pre4;
  if (t0 < 64) ((uint4*)elds)[t0] = e4[bbase + t0];
  if (t0 < 32) hfp8[t0] = 0u;
  __syncthreads();
  do_pregemm();
  load_pb();
  if (t0 < 64 && kNCh > 1) pre4 = e4[bbase + (size_t)kCh * 4 + t0];

  float cs2 = 0.0f, ho = 0.0f;     // cs2 = -2log2e * c_state; ho = 64*tanh(c)*o
  const v4f zero4 = {0.0f, 0.0f, 0.0f, 0.0f};

#pragma unroll 1
  for (int cc = 0; cc < kNCh; ++cc){
#pragma unroll
    for (int s = 0; s < kCh; ++s){
      const int cur = (cc * kCh + s) & 1, nxt = cur ^ 1;

      // A: 32 h-bytes for this lane's k-quad, direct v8i LDS load
      v8i A = *(const v8i*)&hfp8[cur * 32 + q * 8];

      // issue order: tanh-gate first (longest consumer chain), o last
      v4f a2 = __builtin_amdgcn_mfma_scale_f32_16x16x128_f8f6f4(
                   A, B8[2], zero4, 0, 0, 0, 121, 0, 121);
      v4f a0 = __builtin_amdgcn_mfma_scale_f32_16x16x128_f8f6f4(
                   A, B8[0], zero4, 0, 0, 0, 121, 0, 121);
      v4f a1 = __builtin_amdgcn_mfma_scale_f32_16x16x128_f8f6f4(
                   A, B8[1], zero4, 0, 0, 0, 121, 0, 121);
      v4f a3 = __builtin_amdgcn_mfma_scale_f32_16x16x128_f8f6f4(
                   A, B8[3], zero4, 0, 0, 0, 121, 0, 121);

      // all four prescaled gate pre-acts are lane-local (D rows identical)
      float g2 = rcp_fast(1.0f + exp2_f(a2[0] + pb[2][s]));
      float f  = rcp_fast(1.0f + exp2_f(a0[0] + pb[0][s]));
      float ig = rcp_fast(1.0f + exp2_f(a1[0] + pb[1][s]));
      float gg = fmaf(g2, 2.0f, -1.0f);                   // tanh gate
      float t  = ig * gg;
      float og = rcp_fast(1.0f + exp2_f(a3[0] + pb[3][s]));
      cs2 = fmaf(cs2, f, kM2L * t);                       // prescaled c-state
      float rh = rcp_fast(1.0f + exp2_f(cs2));
      ho = fmaf(rh, 128.0f, -64.0f) * og;                 // 64*tanh(c)*o

      if (l < 16){
        uint32_t byte = fp8pair<false>(ho, ho, 0u) & 0xffu;
        ((uint8_t*)&hfp8[nxt * 32])[u] = (uint8_t)byte;
      }
      // last step of chunk: commit prefetched e before the barrier
      if (s == kCh - 1 && cc + 1 < kNCh && t0 < 64) ((uint4*)elds)[t0] = pre4;
      lgkm_barrier();
    }

    if (cc + 1 < kNCh){
      do_pregemm();                // reads elds (barriered), writes preh
      load_pb();                   // intra-wave, lgkmcnt only
      if (t0 < 64 && cc + 2 < kNCh)
        pre4 = e4[bbase + (size_t)(cc + 2) * kCh * 4 + t0];
    }
  }

  // epilogue: out[b] = sigmoid(h_T @ W_out + b_out); h_T = ho/64
  float partial = (l < 16) ? ho * (W_out[u] * 0.015625f) : 0.0f;
#pragma unroll
  for (int off = 1; off <= 32; off <<= 1) partial += __shfl_xor(partial, off, 64);
  if (l == 0) red[w] = partial;
  __syncthreads();
  if (t0 == 0){
    float acc = b_out[0];
#pragma unroll
    for (int k = 0; k < 8; ++k) acc += red[k];
    out[b] = sigmoid_f(acc);
  }
}

extern "C" void kernel_launch(void* const* d_in, const int* in_sizes, int n_in,
                              void* d_out, int out_size, void* d_ws, size_t ws_size,
                              hipStream_t stream){
  const float* x     = (const float*)d_in[0];
  const float* W_emb = (const float*)d_in[1];
  const float* b_emb = (const float*)d_in[2];
  const float* W_f   = (const float*)d_in[3];
  const float* b_f   = (const float*)d_in[4];
  const float* W_i   = (const float*)d_in[5];
  const float* b_i   = (const float*)d_in[6];
  const float* W_c   = (const float*)d_in[7];
  const float* b_c   = (const float*)d_in[8];
  const float* W_o   = (const float*)d_in[9];
  const float* b_o   = (const float*)d_in[10];
  const float* W_out = (const float*)d_in[11];
  const float* b_out = (const float*)d_in[12];
  float* out = (float*)d_out;
  uint32_t* e_ws = (uint32_t*)d_ws;    // B*T*16*4 = 16.8 MB

  const int rows = kB * kT;
  emb_kernel<<<(rows + 255) / 256, 256, 0, stream>>>(x, W_emb, b_emb, e_ws);
  lstm_kernel<<<kB, 512, 0, stream>>>(e_ws, W_f, b_f, W_i, b_i, W_c, b_c,
                                      W_o, b_o, W_out, b_out, out);
}